// Round 9
// baseline (479.951 us; speedup 1.0000x reference)
//
#include <hip/hip_runtime.h>
#include <cstddef>
#include <cstdint>

// Problem constants
#define L_SEQ   2048
#define BATCH_N 4
#define DMODEL  512
#define DINNER  1024
#define DSTATE  8
#define KCONV   4
#define DTRANK  32
#define NBLK    3
#define NCLS_N  10
#define MROWS   (BATCH_N * L_SEQ)   // 8192
#define DBLW    48                  // dt_rank + 2*d_state
#define NSPLIT  8                   // x_proj split-K grid

// Chunked-scan parameters: LC2=32 rows/chunk, d split x4 -> grid (64,4,4)
// = 1024 blocks x 256 thr (memory-bound; ILP from 32-row unroll covers
// the 16-wave/CU occupancy). PSbuf/Hbuf halve vs LC2=16.
#define LC2 32
#define NC2 (L_SEQ / LC2)   // 64
#define DQ  (DINNER / 4)    // 256 cols per block
#define SCAN_THREADS 256
#define SCAN_WAVES   (SCAN_THREADS / 64)   // 4
#define DBLP 52                     // padded row stride for sDbl (2-way max conflict)

// 2-level combine: 8 waves x 8-chunk segments
#define CGRP 8
#define CPG  (NC2 / CGRP)   // 8

typedef __attribute__((ext_vector_type(8))) short bf16x8;
typedef __attribute__((ext_vector_type(4))) short bf16x4;
typedef __attribute__((ext_vector_type(2))) short bf16x2;
typedef __attribute__((ext_vector_type(4))) float f32x4;

// Fast inline transcendentals (v_exp_f32 / v_log_f32 — no ocml calls).
__device__ __forceinline__ float sigmoid_fast(float x) { return 1.f / (1.f + __expf(-x)); }
__device__ __forceinline__ float silu_fast(float x)    { return x * sigmoid_fast(x); }
__device__ __forceinline__ float softplus_fast(float x){
    return fmaxf(x, 0.f) + __logf(1.f + __expf(-fabsf(x)));
}
// exp2 (v_exp_f32 directly; log2e pre-folded into the coefficient)
__device__ __forceinline__ float exp2_fast(float x) {
#if __has_builtin(__builtin_amdgcn_exp2f)
    return __builtin_amdgcn_exp2f(x);
#else
    return __expf(x * 0.69314718055994531f);
#endif
}
#define LOG2E 1.44269504088896341f

__device__ __forceinline__ unsigned short f2bf(float f) {
    union { float f; uint32_t u; } v; v.f = f;
    const uint32_t u = v.u;
    return (unsigned short)((u + 0x7fffu + ((u >> 16) & 1u)) >> 16);  // RNE
}
__device__ __forceinline__ float bf2f(unsigned short h) {
    union { uint32_t u; float f; } v; v.u = ((uint32_t)h) << 16;
    return v.f;
}
__device__ __forceinline__ float bf2f_s(short h) { return bf2f((unsigned short)h); }

// async global -> LDS, 16 bytes per lane
__device__ __forceinline__ void load_lds16(const void* g, void* l) {
    __builtin_amdgcn_global_load_lds(
        (const __attribute__((address_space(1))) unsigned int*)g,
        (__attribute__((address_space(3))) unsigned int*)l,
        16, 0, 0);
}

// ---------------------------------------------------------------------------
// bf16 MFMA GEMM: acc = A[M,K] @ Bt[N,K]^T, 128 x NT tile, BK=64, 256 thr.
// Single-buffered staging; XOR-swizzled LDS; LDS-bounced coalesced epilogue.
// XCD-aware bijective block swizzle for per-XCD L2 locality.
//   EPI = 0: Obf = bf16(acc)
//   EPI = 2: v = acc + bf2f(Obf) (bf16 residual, in-place)
//   EPI = 3: as 2, plus column sums atomicAdd'ed into pool[b][col]
// ---------------------------------------------------------------------------
template <int K, int NT, int EPI>
__global__ __launch_bounds__(256) void gemm_bf16(
    const unsigned short* __restrict__ A, int lda,
    const unsigned short* __restrict__ Bt, int ldb,
    int ldc,
    unsigned short* __restrict__ Obf,
    float* __restrict__ pool)
{
    constexpr int BCH   = NT / 8;
    constexpr int NTW   = NT / 32;
    constexpr int STAGE = 8192 + NT * 64;
    constexpr int EPIL  = 128 * (NT + 8);
    constexpr int SMEM  = (STAGE > EPIL) ? STAGE : EPIL;
    __shared__ unsigned short sMem[SMEM];
    unsigned short* sA = sMem;
    unsigned short* sB = sMem + 8192;

    const int tid  = threadIdx.x;
    const int lane = tid & 63;
    const int wave = tid >> 6;

    // bijective XCD swizzle (8 XCDs)
    const int nwgx = gridDim.x;
    const int nwg  = nwgx * gridDim.y;
    int flat = blockIdx.y * nwgx + blockIdx.x;
    {
        const int q = nwg >> 3, r = nwg & 7;
        const int xcd = flat & 7, lid = flat >> 3;
        flat = (xcd < r ? xcd * (q + 1) : r * (q + 1) + (xcd - r) * q) + lid;
    }
    const int m0 = (flat / nwgx) * 128;
    const int n0 = (flat % nwgx) * NT;

    const int wm = (wave >> 1) * 64;
    const int wn = (wave & 1) * (NT / 2);
    const int lm = lane & 15;
    const int lq = lane >> 4;

    const int srow = lane >> 3;
    const int scol = ((lane & 7) ^ srow) * 8;

    f32x4 acc[4][NTW];
    #pragma unroll
    for (int i = 0; i < 4; ++i)
        #pragma unroll
        for (int j = 0; j < NTW; ++j) acc[i][j] = (f32x4){0.f, 0.f, 0.f, 0.f};

    for (int k0 = 0; k0 < K; k0 += 64) {
        #pragma unroll
        for (int c = wave; c < 16; c += 4)
            load_lds16(A + (size_t)(m0 + c * 8 + srow) * lda + k0 + scol, &sA[c * 512]);
        #pragma unroll
        for (int c = wave; c < BCH; c += 4)
            load_lds16(Bt + (size_t)(n0 + c * 8 + srow) * ldb + k0 + scol, &sB[c * 512]);
        __syncthreads();
        #pragma unroll
        for (int ks = 0; ks < 2; ++ks) {
            bf16x8 aF[4], bF[NTW];
            #pragma unroll
            for (int mt = 0; mt < 4; ++mt) {
                const int row = wm + mt * 16 + lm;
                aF[mt] = *(const bf16x8*)&sA[row * 64 + (((ks * 4 + lq) ^ (lm & 7)) * 8)];
            }
            #pragma unroll
            for (int nt = 0; nt < NTW; ++nt) {
                const int row = wn + nt * 16 + lm;
                bF[nt] = *(const bf16x8*)&sB[row * 64 + (((ks * 4 + lq) ^ (lm & 7)) * 8)];
            }
            #pragma unroll
            for (int mt = 0; mt < 4; ++mt)
                #pragma unroll
                for (int nt = 0; nt < NTW; ++nt)
                    acc[mt][nt] = __builtin_amdgcn_mfma_f32_16x16x32_bf16(
                        aF[mt], bF[nt], acc[mt][nt], 0, 0, 0);
        }
        __syncthreads();
    }

    unsigned short* sOut = sMem;
    #pragma unroll
    for (int mt = 0; mt < 4; ++mt) {
        #pragma unroll
        for (int nt = 0; nt < NTW; ++nt) {
            #pragma unroll
            for (int r = 0; r < 4; ++r) {
                const int row = wm + mt * 16 + lq * 4 + r;
                const int col = wn + nt * 16 + lm;
                float v = acc[mt][nt][r];
                if (EPI >= 2) {
                    const size_t gi = (size_t)(m0 + row) * ldc + n0 + col;
                    v += bf2f(Obf[gi]);   // bf16 residual read (write comes after barrier)
                }
                sOut[row * (NT + 8) + col] = f2bf(v);
            }
        }
    }
    __syncthreads();
    #pragma unroll
    for (int j = 0; j < NT / 16; ++j) {
        const int idx = j * 256 + tid;
        const int row = idx / (NT / 8);
        const int cpos = (idx % (NT / 8)) * 8;
        *(bf16x8*)&Obf[(size_t)(m0 + row) * ldc + n0 + cpos] =
            *(const bf16x8*)&sOut[row * (NT + 8) + cpos];
    }
    if (EPI == 3) {
        const int b = m0 >> 11;
        const int col = tid & (NT - 1);
        const int q = tid / NT;
        constexpr int RPQ = 128 / (256 / NT);
        float s = 0.f;
        #pragma unroll
        for (int r = q * RPQ; r < (q + 1) * RPQ; ++r)
            s += bf2f(sOut[r * (NT + 8) + col]);
        atomicAdd(&pool[b * DMODEL + n0 + col], s);
    }
}

// ---------------------------------------------------------------------------
// Fused conv+SiLU+x_proj: each block owns a 64-row x 128-col (d) tile.
// Phase 1: conv(K=4)+bias+SiLU -> swizzled LDS tile + coalesced ub write.
// Phase 2: Xp[split][rows][48] = tile @ Wxt[48, k-slice]^T via MFMA from LDS.
// ---------------------------------------------------------------------------
__global__ __launch_bounds__(256) void conv_xproj_kernel(
    const unsigned short* __restrict__ xz,
    const float* __restrict__ cwt,   // (4, 1024)
    const float* __restrict__ cb,
    const unsigned short* __restrict__ Wxt,
    unsigned short* __restrict__ ub,
    float* __restrict__ Xp)
{
    __shared__ unsigned short sU[64 * 128];   // 16 KB, XOR-swizzled chunks
    const int tid = threadIdx.x, lane = tid & 63, wave = tid >> 6;
    const int lm = lane & 15, lq = lane >> 4;
    const int row0 = blockIdx.x * 64;
    const int split = blockIdx.y;
    const int k0 = split * (DINNER / NSPLIT);   // 128-col d-slice

    // ---- Phase 1: conv + SiLU
    const int cj  = tid & 15;          // col chunk (8 cols each)
    const int rr0 = tid >> 4;          // row 0..15, + p*16
    const int dcol = k0 + cj * 8;
    float4 cb0 = *(const float4*)&cb[dcol];
    float4 cb1 = *(const float4*)&cb[dcol + 4];
    float4 w0[KCONV], w1[KCONV];
    #pragma unroll
    for (int k = 0; k < KCONV; ++k) {
        w0[k] = *(const float4*)&cwt[k * DINNER + dcol];
        w1[k] = *(const float4*)&cwt[k * DINNER + dcol + 4];
    }
    #pragma unroll
    for (int p = 0; p < 4; ++p) {
        const int rl = p * 16 + rr0;
        const int m  = row0 + rl;
        const int t  = m & (L_SEQ - 1);
        float acc[8];
        acc[0] = cb0.x; acc[1] = cb0.y; acc[2] = cb0.z; acc[3] = cb0.w;
        acc[4] = cb1.x; acc[5] = cb1.y; acc[6] = cb1.z; acc[7] = cb1.w;
        #pragma unroll
        for (int k = 0; k < KCONV; ++k) {
            if (t + k - (KCONV - 1) >= 0) {
                bf16x8 xv = *(const bf16x8*)&xz[(size_t)(m + k - (KCONV - 1)) * (2 * DINNER) + dcol];
                acc[0] = fmaf(bf2f_s(xv[0]), w0[k].x, acc[0]);
                acc[1] = fmaf(bf2f_s(xv[1]), w0[k].y, acc[1]);
                acc[2] = fmaf(bf2f_s(xv[2]), w0[k].z, acc[2]);
                acc[3] = fmaf(bf2f_s(xv[3]), w0[k].w, acc[3]);
                acc[4] = fmaf(bf2f_s(xv[4]), w1[k].x, acc[4]);
                acc[5] = fmaf(bf2f_s(xv[5]), w1[k].y, acc[5]);
                acc[6] = fmaf(bf2f_s(xv[6]), w1[k].z, acc[6]);
                acc[7] = fmaf(bf2f_s(xv[7]), w1[k].w, acc[7]);
            }
        }
        bf16x8 o;
        #pragma unroll
        for (int j = 0; j < 8; ++j) o[j] = (short)f2bf(silu_fast(acc[j]));
        *(bf16x8*)&ub[(size_t)m * DINNER + dcol] = o;
        *(bf16x8*)&sU[rl * 128 + ((cj ^ (rl & 7)) * 8)] = o;
    }
    __syncthreads();

    // ---- Phase 2: MFMA x_proj from LDS tile
    const int rowA = row0 + wave * 16;
    f32x4 acc3[3];
    #pragma unroll
    for (int j = 0; j < 3; ++j) acc3[j] = (f32x4){0.f, 0.f, 0.f, 0.f};

    #pragma unroll
    for (int kk = 0; kk < DINNER / NSPLIT; kk += 32) {
        const int rl = wave * 16 + lm;
        bf16x8 aF = *(const bf16x8*)&sU[rl * 128 + ((((kk >> 3) + lq) ^ (lm & 7)) * 8)];
        bf16x8 bF[3];
        #pragma unroll
        for (int nt = 0; nt < 3; ++nt)
            bF[nt] = *(const bf16x8*)&Wxt[(size_t)(nt * 16 + lm) * DINNER + k0 + kk + lq * 8];
        #pragma unroll
        for (int nt = 0; nt < 3; ++nt)
            acc3[nt] = __builtin_amdgcn_mfma_f32_16x16x32_bf16(
                aF, bF[nt], acc3[nt], 0, 0, 0);
    }
    float* dst = Xp + (size_t)split * MROWS * DBLW;
    #pragma unroll
    for (int nt = 0; nt < 3; ++nt)
        #pragma unroll
        for (int r = 0; r < 4; ++r)
            dst[(size_t)(rowA + lq * 4 + r) * DBLW + nt * 16 + lm] = acc3[nt][r];
}

// ---------------------------------------------------------------------------
// Weight transpose + cast: out[n][k] bf16 = in[k][n] fp32
// ---------------------------------------------------------------------------
__global__ __launch_bounds__(256) void transpose_cast(
    const float* __restrict__ in, unsigned short* __restrict__ out,
    int Kdim, int Ndim, size_t in_stride, size_t out_stride)
{
    __shared__ float s[32][33];
    const float* ip = in + blockIdx.z * in_stride;
    unsigned short* op = out + blockIdx.z * out_stride;
    const int bx = blockIdx.x * 32;
    const int by = blockIdx.y * 32;
    const int t = threadIdx.x;
    const int r = t >> 3;
    const int c4 = (t & 7) * 4;

    const int row = by + r;
    if (bx + c4 + 3 < Ndim) {
        float4 v = *(const float4*)&ip[(size_t)row * Ndim + bx + c4];
        s[r][c4 + 0] = v.x; s[r][c4 + 1] = v.y; s[r][c4 + 2] = v.z; s[r][c4 + 3] = v.w;
    } else {
        for (int i = 0; i < 4; ++i) {
            const int col = bx + c4 + i;
            s[r][c4 + i] = (col < Ndim) ? ip[(size_t)row * Ndim + col] : 0.f;
        }
    }
    __syncthreads();
    if (bx + r < Ndim) {
        unsigned short w0 = f2bf(s[c4 + 0][r]), w1 = f2bf(s[c4 + 1][r]);
        unsigned short w2 = f2bf(s[c4 + 2][r]), w3 = f2bf(s[c4 + 3][r]);
        uint2 pk;
        pk.x = (uint32_t)w0 | ((uint32_t)w1 << 16);
        pk.y = (uint32_t)w2 | ((uint32_t)w3 << 16);
        *(uint2*)&op[(size_t)(bx + r) * Kdim + by + c4] = pk;
    }
}

// cast x -> xb (bf16); zero pooled_accum; negA prep; conv-w transpose.
__global__ void cast_init(const float* __restrict__ in, unsigned short* __restrict__ outb,
                          float* __restrict__ pooled_accum,
                          const float* __restrict__ A_log, float* __restrict__ negA,
                          const float* __restrict__ cw, float* __restrict__ cwt,
                          int n4) {
    const int i = blockIdx.x * 256 + threadIdx.x;
    if (i < BATCH_N * DMODEL / 4)
        ((f32x4*)pooled_accum)[i] = (f32x4){0.f, 0.f, 0.f, 0.f};
    if (i < NBLK * DINNER * DSTATE)
        negA[i] = -__expf(A_log[i]) * LOG2E;
    if (i < NBLK * DINNER * KCONV) {
        const int blk = i >> 12;
        const int rem = i & 4095;
        const int d = rem >> 2;
        const int k = rem & 3;
        cwt[blk * 4096 + k * DINNER + d] = cw[blk * 4096 + d * KCONV + k];
    }
    if (i >= n4) return;
    float4 v = ((const float4*)in)[i];
    uint2 pk;
    pk.x = (uint32_t)f2bf(v.x) | ((uint32_t)f2bf(v.y) << 16);
    pk.y = (uint32_t)f2bf(v.z) | ((uint32_t)f2bf(v.w) << 16);
    ((uint2*)outb)[i] = pk;
}

// ---------------------------------------------------------------------------
// dt-proj recompute into LDS for one d-quarter: delta[32][256] bf16 =
// softplus(dblsum[:, :32] @ Wdtt^T + bdt). 2 MFMA m-tiles x 4 waves x 4
// col-tiles = 32 MFMAs/block. Per-row values bit-identical to the LC2=16
// version (MFMA rows are independent of tile grouping).
// ---------------------------------------------------------------------------
__device__ __forceinline__ void dt_recompute_lds(
    unsigned short* sDelta,                  // LC2 * DQ bf16
    const float* sDbl,                       // LC2 x DBLP (LDS)
    const unsigned short* __restrict__ Wdtt, // (1024, 32) bf16
    const float* __restrict__ bdt,
    int lane, int wave, int dbase)
{
    const int lm = lane & 15, lq = lane >> 4;
    #pragma unroll
    for (int mt = 0; mt < LC2 / 16; ++mt) {
        bf16x8 aF;
        {
            const float* p = &sDbl[(mt * 16 + lm) * DBLP + lq * 8];
            float4 x0 = *(const float4*)p;
            float4 x1 = *(const float4*)(p + 4);
            aF[0] = (short)f2bf(x0.x); aF[1] = (short)f2bf(x0.y);
            aF[2] = (short)f2bf(x0.z); aF[3] = (short)f2bf(x0.w);
            aF[4] = (short)f2bf(x1.x); aF[5] = (short)f2bf(x1.y);
            aF[6] = (short)f2bf(x1.z); aF[7] = (short)f2bf(x1.w);
        }
        constexpr int NPW = DQ / (16 * SCAN_WAVES);   // 4 col16-tiles per wave
        #pragma unroll
        for (int nt = 0; nt < NPW; ++nt) {
            const int cloc = wave * (DQ / SCAN_WAVES) + nt * 16;   // local col
            const int col16 = dbase + cloc;
            bf16x8 bF = *(const bf16x8*)&Wdtt[(size_t)(col16 + lm) * DTRANK + lq * 8];
            f32x4 acc = (f32x4){0.f, 0.f, 0.f, 0.f};
            acc = __builtin_amdgcn_mfma_f32_16x16x32_bf16(aF, bF, acc, 0, 0, 0);
            const float bias = bdt[col16 + lm];
            #pragma unroll
            for (int r = 0; r < 4; ++r)
                sDelta[(mt * 16 + lq * 4 + r) * DQ + cloc + lm] =
                    f2bf(softplus_fast(acc[r] + bias));
        }
    }
}

// Stage the 8-way-reduced x_proj rows for this chunk into sDbl[32][DBLP].
// Same summation order (sp = 0..7) as before -> bit-identical.
__device__ __forceinline__ void stage_dbl_rows(
    float* sDbl, const float* __restrict__ Xp, size_t m0, int tid)
{
    for (int idx = tid; idx < LC2 * DBLW; idx += SCAN_THREADS) {
        const int mr = idx / DBLW, j = idx - mr * DBLW;
        float s = 0.f;
        #pragma unroll
        for (int sp = 0; sp < NSPLIT; ++sp)
            s += Xp[((size_t)sp * MROWS + m0 + mr) * DBLW + j];
        sDbl[mr * DBLP + j] = s;
    }
}

// Detect a[n] == (n+1)*a[0] (canonical Mamba A_log = log(arange(1..N)) init);
// falls back to the general 8-exp path when the structure doesn't hold.
__device__ __forceinline__ bool a_is_arange(const float* a) {
    bool pw = true;
    #pragma unroll
    for (int n = 1; n < DSTATE; ++n)
        pw = pw && (fabsf(a[n] - (float)(n + 1) * a[0]) <=
                    1e-5f * (float)(n + 1) * fabsf(a[0]));
    return pw;
}

// ---------------------------------------------------------------------------
// 3-phase chunked selective scan; 256 threads, 1 channel/thread, d split x4.
// Grid (NC2, 4, BATCH) = 1024 blocks.
// ---------------------------------------------------------------------------
__global__ __launch_bounds__(SCAN_THREADS) void scan_chunk_kernel(
    const unsigned short* __restrict__ ub,
    const float* __restrict__ Xp,
    const unsigned short* __restrict__ Wdtt,
    const float* __restrict__ bdt,
    const float* __restrict__ negA,          // (1024, 8) = -exp(A_log)*log2e
    float* __restrict__ PSbuf)
{
    const int c  = blockIdx.x;
    const int dq = blockIdx.y;
    const int b  = blockIdx.z;
    const int tid = threadIdx.x;
    const int lane = tid & 63;
    const int wave = tid >> 6;
    const int dbase = dq * DQ;
    const int d = dbase + tid;

    __shared__ unsigned short sDelta[LC2 * DQ];
    __shared__ float sDbl[LC2 * DBLP];

    const size_t m0 = (size_t)b * L_SEQ + c * LC2;

    stage_dbl_rows(sDbl, Xp, m0, tid);
    __syncthreads();
    dt_recompute_lds(sDelta, sDbl, Wdtt, bdt, lane, wave, dbase);
    __syncthreads();

    float a[DSTATE], S[DSTATE];
    {
        float4 a0 = *(const float4*)&negA[(size_t)d * DSTATE];
        float4 a1 = *(const float4*)&negA[(size_t)d * DSTATE + 4];
        a[0] = a0.x; a[1] = a0.y; a[2] = a0.z; a[3] = a0.w;
        a[4] = a1.x; a[5] = a1.y; a[6] = a1.z; a[7] = a1.w;
    }
    #pragma unroll
    for (int n = 0; n < DSTATE; ++n) S[n] = 0.f;
    float dtsum = 0.f;

    if (a_is_arange(a)) {
        for (int r = 0; r < LC2; ++r) {
            const size_t m = m0 + r;
            const float dt = bf2f(sDelta[r * DQ + tid]);
            const float du = dt * bf2f(ub[m * DINNER + d]);
            dtsum += dt;
            const float e1 = exp2_fast(dt * a[0]);
            float e = e1;
            #pragma unroll
            for (int n = 0; n < DSTATE; ++n) {
                S[n] = fmaf(e, S[n], du * sDbl[r * DBLP + DTRANK + n]);
                e *= e1;
            }
        }
        const size_t nb = (size_t)(b * NC2 + c) * DSTATE;
        const float P1 = exp2_fast(a[0] * dtsum);
        float p = P1;
        #pragma unroll
        for (int n = 0; n < DSTATE; ++n) {
            float2 ps; ps.x = p; ps.y = S[n];
            *(float2*)&PSbuf[(nb + n) * (DINNER * 2) + (size_t)d * 2] = ps;
            p *= P1;
        }
    } else {
        for (int r = 0; r < LC2; ++r) {
            const size_t m = m0 + r;
            const float dt = bf2f(sDelta[r * DQ + tid]);
            const float du = dt * bf2f(ub[m * DINNER + d]);
            dtsum += dt;
            #pragma unroll
            for (int n = 0; n < DSTATE; ++n) {
                const float e = exp2_fast(dt * a[n]);
                S[n] = fmaf(e, S[n], du * sDbl[r * DBLP + DTRANK + n]);
            }
        }
        const size_t nb = (size_t)(b * NC2 + c) * DSTATE;
        #pragma unroll
        for (int n = 0; n < DSTATE; ++n) {
            float2 ps; ps.x = exp2_fast(a[n] * dtsum); ps.y = S[n];
            *(float2*)&PSbuf[(nb + n) * (DINNER * 2) + (size_t)d * 2] = ps;
        }
    }
}

// Combine: h-recurrence over chunks, 2-level (8 waves x 8-chunk segments).
// Segment (P,S) pairs register-cached (fully unrolled) -> PSbuf read once.
__global__ __launch_bounds__(512) void scan_combine_kernel(
    const float* __restrict__ PSbuf,
    float* __restrict__ Hbuf)
{
    const int dl = threadIdx.x & 63;
    const int g  = threadIdx.x >> 6;
    const int d  = blockIdx.x * 64 + dl;
    const int n  = blockIdx.y;
    const int b  = blockIdx.z;

    __shared__ float sP[CGRP][64];
    __shared__ float sS[CGRP][64];

    const int c0 = g * CPG;
    float2 psr[CPG];
    float Pseg = 1.f, Sseg = 0.f;
    #pragma unroll
    for (int cc = 0; cc < CPG; ++cc) {
        const size_t row = (size_t)(b * NC2 + c0 + cc) * DSTATE + n;
        psr[cc] = *(const float2*)&PSbuf[row * (DINNER * 2) + (size_t)d * 2];
        Pseg *= psr[cc].x;
        Sseg = fmaf(psr[cc].x, Sseg, psr[cc].y);
    }
    sP[g][dl] = Pseg;
    sS[g][dl] = Sseg;
    __syncthreads();

    float h = 0.f;
    for (int gg = 0; gg < g; ++gg)            // wave-uniform trip count
        h = fmaf(sP[gg][dl], h, sS[gg][dl]);

    #pragma unroll
    for (int cc = 0; cc < CPG; ++cc) {
        const size_t row = (size_t)(b * NC2 + c0 + cc) * DSTATE + n;
        Hbuf[row * DINNER + d] = h;
        h = fmaf(psr[cc].x, h, psr[cc].y);
    }
}

__global__ __launch_bounds__(SCAN_THREADS) void scan_out_kernel(
    const unsigned short* __restrict__ ub,
    const float* __restrict__ Xp,
    const unsigned short* __restrict__ Wdtt,
    const float* __restrict__ bdt,
    const unsigned short* __restrict__ xz,   // z at [., 1024+d]
    const float* __restrict__ negA,
    const float* __restrict__ Dp,
    const float* __restrict__ Hin,
    unsigned short* __restrict__ ybuf)
{
    const int c  = blockIdx.x;
    const int dq = blockIdx.y;
    const int b  = blockIdx.z;
    const int tid = threadIdx.x;
    const int lane = tid & 63;
    const int wave = tid >> 6;
    const int dbase = dq * DQ;
    const int d = dbase + tid;

    __shared__ unsigned short sDelta[LC2 * DQ];
    __shared__ float sDbl[LC2 * DBLP];

    const size_t m0 = (size_t)b * L_SEQ + c * LC2;

    stage_dbl_rows(sDbl, Xp, m0, tid);
    __syncthreads();
    dt_recompute_lds(sDelta, sDbl, Wdtt, bdt, lane, wave, dbase);
    __syncthreads();

    float a[DSTATE], h[DSTATE];
    {
        float4 a0 = *(const float4*)&negA[(size_t)d * DSTATE];
        float4 a1 = *(const float4*)&negA[(size_t)d * DSTATE + 4];
        a[0] = a0.x; a[1] = a0.y; a[2] = a0.z; a[3] = a0.w;
        a[4] = a1.x; a[5] = a1.y; a[6] = a1.z; a[7] = a1.w;
    }
    const size_t base = ((size_t)(b * NC2 + c) * DSTATE) * DINNER + d;
    #pragma unroll
    for (int n = 0; n < DSTATE; ++n)
        h[n] = Hin[base + (size_t)n * DINNER];
    const float Dd = Dp[d];

    if (a_is_arange(a)) {
        for (int r = 0; r < LC2; ++r) {
            const size_t m = m0 + r;
            const float dt = bf2f(sDelta[r * DQ + tid]);
            const float ut = bf2f(ub[m * DINNER + d]);
            const float zt = bf2f(xz[m * (2 * DINNER) + DINNER + d]);
            const float du = dt * ut;
            const float e1 = exp2_fast(dt * a[0]);
            float e = e1;
            float acc = 0.f;
            #pragma unroll
            for (int n = 0; n < DSTATE; ++n) {
                h[n] = fmaf(e, h[n], du * sDbl[r * DBLP + DTRANK + n]);
                acc = fmaf(h[n], sDbl[r * DBLP + DTRANK + DSTATE + n], acc);
                e *= e1;
            }
            ybuf[m * DINNER + d] = f2bf(fmaf(ut, Dd, acc) * silu_fast(zt));
        }
    } else {
        for (int r = 0; r < LC2; ++r) {
            const size_t m = m0 + r;
            const float dt = bf2f(sDelta[r * DQ + tid]);
            const float ut = bf2f(ub[m * DINNER + d]);
            const float zt = bf2f(xz[m * (2 * DINNER) + DINNER + d]);
            const float du = dt * ut;
            float acc = 0.f;
            #pragma unroll
            for (int n = 0; n < DSTATE; ++n) {
                const float e = exp2_fast(dt * a[n]);
                h[n] = fmaf(e, h[n], du * sDbl[r * DBLP + DTRANK + n]);
                acc = fmaf(h[n], sDbl[r * DBLP + DTRANK + DSTATE + n], acc);
            }
            ybuf[m * DINNER + d] = f2bf(fmaf(ut, Dd, acc) * silu_fast(zt));
        }
    }
}

// ---------------------------------------------------------------------------
// pooled-sum (from fused out_proj accumulation) + classifier
// ---------------------------------------------------------------------------
__global__ __launch_bounds__(512) void pool_cls_kernel(
    const float* __restrict__ pooled_accum,   // (B, 512) sums over t
    const float* __restrict__ w,              // (512, 10)
    const float* __restrict__ bias,           // (10,)
    float* __restrict__ out)
{
    __shared__ float sp[DMODEL];
    const int b = blockIdx.x;
    const int dm = threadIdx.x;
    sp[dm] = pooled_accum[b * DMODEL + dm] * (1.f / (float)L_SEQ);
    __syncthreads();
    if (dm < NCLS_N) {
        float acc = bias[dm];
        for (int k = 0; k < DMODEL; ++k)
            acc = fmaf(sp[k], w[k * NCLS_N + dm], acc);
        out[b * NCLS_N + dm] = acc;
    }
}

// ---------------------------------------------------------------------------
extern "C" void kernel_launch(void* const* d_in, const int* in_sizes, int n_in,
                              void* d_out, int out_size, void* d_ws, size_t ws_size,
                              hipStream_t stream) {
    const float* x_in      = (const float*)d_in[0];
    const float* in_proj_w = (const float*)d_in[1];
    const float* conv_w    = (const float*)d_in[2];
    const float* conv_b    = (const float*)d_in[3];
    const float* x_proj_w  = (const float*)d_in[4];
    const float* dt_proj_w = (const float*)d_in[5];
    const float* dt_proj_b = (const float*)d_in[6];
    const float* A_log     = (const float*)d_in[7];
    const float* Dp        = (const float*)d_in[8];
    const float* out_proj_w= (const float*)d_in[9];
    const float* cls_w     = (const float*)d_in[10];
    const float* cls_b     = (const float*)d_in[11];
    float* out = (float*)d_out;

    // Workspace layout (bytes, 256-aligned)
    char* w = (char*)d_ws;
    auto alloc = [&](size_t bytes) { char* p = w; w += (bytes + 255) & ~(size_t)255; return p; };
    unsigned short* xz_bf  = (unsigned short*)alloc((size_t)MROWS * 2 * DINNER * 2);
    unsigned short* ub     = (unsigned short*)alloc((size_t)MROWS * DINNER * 2);
    float*          Xp     = (float*)         alloc((size_t)NSPLIT * MROWS * DBLW * 4);
    float*          PSbuf  = (float*)         alloc((size_t)BATCH_N * NC2 * DSTATE * DINNER * 2 * 4);
    float*          Hbuf   = (float*)         alloc((size_t)BATCH_N * NC2 * DSTATE * DINNER * 4);
    unsigned short* xb     = (unsigned short*)alloc((size_t)MROWS * DMODEL * 2);
    unsigned short* ybuf   = (unsigned short*)alloc((size_t)MROWS * DINNER * 2);
    unsigned short* Wit    = (unsigned short*)alloc((size_t)NBLK * 2048 * 512 * 2);
    unsigned short* Wot    = (unsigned short*)alloc((size_t)NBLK * 512 * 1024 * 2);
    unsigned short* Wxt    = (unsigned short*)alloc((size_t)NBLK * DBLW * 1024 * 2);
    unsigned short* Wdtt   = (unsigned short*)alloc((size_t)NBLK * 1024 * DTRANK * 2);
    float*          cwt    = (float*)         alloc((size_t)NBLK * KCONV * DINNER * 4);
    float*          negA   = (float*)         alloc((size_t)NBLK * DINNER * DSTATE * 4);
    float*          pooled = (float*)         alloc((size_t)BATCH_N * DMODEL * 4);

    // Prep (cast_init also zeroes pooled, builds negA and cwt)
    cast_init<<<(MROWS * DMODEL / 4) / 256, 256, 0, stream>>>(
        x_in, xb, pooled, A_log, negA, conv_w, cwt, MROWS * DMODEL / 4);
    transpose_cast<<<dim3(2048 / 32, 512 / 32, NBLK), 256, 0, stream>>>(
        in_proj_w, Wit, 512, 2048, (size_t)512 * 2048, (size_t)2048 * 512);
    transpose_cast<<<dim3(512 / 32, 1024 / 32, NBLK), 256, 0, stream>>>(
        out_proj_w, Wot, 1024, 512, (size_t)1024 * 512, (size_t)512 * 1024);
    transpose_cast<<<dim3(2, 1024 / 32, NBLK), 256, 0, stream>>>(
        x_proj_w, Wxt, 1024, DBLW, (size_t)1024 * DBLW, (size_t)DBLW * 1024);
    transpose_cast<<<dim3(1024 / 32, 1, NBLK), 256, 0, stream>>>(
        dt_proj_w, Wdtt, DTRANK, 1024, (size_t)DTRANK * 1024, (size_t)1024 * DTRANK);

    for (int blk = 0; blk < NBLK; ++blk) {
        const unsigned short* Wit_b  = Wit  + (size_t)blk * 2048 * 512;
        const unsigned short* Wot_b  = Wot  + (size_t)blk * 512 * 1024;
        const unsigned short* Wxt_b  = Wxt  + (size_t)blk * DBLW * 1024;
        const unsigned short* Wdtt_b = Wdtt + (size_t)blk * 1024 * DTRANK;
        const float* cwt_b = cwt + (size_t)blk * KCONV * DINNER;
        const float* cb  = conv_b    + (size_t)blk * DINNER;
        const float* bdt = dt_proj_b + (size_t)blk * DINNER;
        const float* nA  = negA      + (size_t)blk * DINNER * DSTATE;
        const float* Dv  = Dp        + (size_t)blk * DINNER;

        // 1) xz_bf = bf16(xb @ Wit^T)   K=512, 128x128 tiles
        gemm_bf16<512, 128, 0><<<dim3(2048 / 128, MROWS / 128), 256, 0, stream>>>(
            xb, DMODEL, Wit_b, DMODEL, 2 * DINNER, xz_bf, nullptr);
        // 2+3) fused conv+SiLU -> ub, then Xp[s] partials from LDS tile
        conv_xproj_kernel<<<dim3(MROWS / 64, NSPLIT), 256, 0, stream>>>(
            xz_bf, cwt_b, cb, Wxt_b, ub, Xp);
        // 4) chunked scan; LC2=32 chunks, d split x4
        {
            dim3 gridA(NC2, DINNER / DQ, BATCH_N);
            scan_chunk_kernel<<<gridA, SCAN_THREADS, 0, stream>>>(
                ub, Xp, Wdtt_b, bdt, nA, PSbuf);
            scan_combine_kernel<<<dim3(DINNER / 64, DSTATE, BATCH_N), 512, 0, stream>>>(
                PSbuf, Hbuf);
            scan_out_kernel<<<gridA, SCAN_THREADS, 0, stream>>>(
                ub, Xp, Wdtt_b, bdt, xz_bf, nA, Dv, Hbuf, ybuf);
        }
        // 5) xb += ybuf @ Wot^T (bf16 residual in-place); last block also
        //    accumulates the mean-pool column sums into pooled[]
        if (blk < NBLK - 1)
            gemm_bf16<1024, 64, 2><<<dim3(DMODEL / 64, MROWS / 128), 256, 0, stream>>>(
                ybuf, DINNER, Wot_b, DINNER, DMODEL, xb, nullptr);
        else
            gemm_bf16<1024, 64, 3><<<dim3(DMODEL / 64, MROWS / 128), 256, 0, stream>>>(
                ybuf, DINNER, Wot_b, DINNER, DMODEL, xb, pooled);
    }

    // classifier on pooled sums
    pool_cls_kernel<<<BATCH_N, DMODEL, 0, stream>>>(pooled, cls_w, cls_b, out);
}

// Round 10
// 443.518 us; speedup vs baseline: 1.0821x; 1.0821x over previous
//
#include <hip/hip_runtime.h>
#include <cstddef>
#include <cstdint>

// Problem constants
#define L_SEQ   2048
#define BATCH_N 4
#define DMODEL  512
#define DINNER  1024
#define DSTATE  8
#define KCONV   4
#define DTRANK  32
#define NBLK    3
#define NCLS_N  10
#define MROWS   (BATCH_N * L_SEQ)   // 8192
#define DBLW    48                  // dt_rank + 2*d_state
#define NSPLIT  8                   // x_proj split-K grid

// Chunked-scan parameters: LC2=16 rows/chunk, d split x2 -> 1024 blocks (4/CU)
#define LC2 16
#define NC2 (L_SEQ / LC2)   // 128
#define DHALF (DINNER / 2)  // 512 cols per block
#define SCAN_THREADS 512
#define SCAN_WAVES   (SCAN_THREADS / 64)   // 8
#define DBLP 52                     // padded row stride for sDbl (2-way max conflict)

// 2-level combine: 8 waves x 16-chunk segments
#define CGRP 8
#define CPG  (NC2 / CGRP)   // 16

typedef __attribute__((ext_vector_type(8))) short bf16x8;
typedef __attribute__((ext_vector_type(4))) short bf16x4;
typedef __attribute__((ext_vector_type(2))) short bf16x2;
typedef __attribute__((ext_vector_type(4))) float f32x4;

// Fast inline transcendentals (v_exp_f32 / v_log_f32 — no ocml calls).
__device__ __forceinline__ float sigmoid_fast(float x) { return 1.f / (1.f + __expf(-x)); }
__device__ __forceinline__ float silu_fast(float x)    { return x * sigmoid_fast(x); }
__device__ __forceinline__ float softplus_fast(float x){
    return fmaxf(x, 0.f) + __logf(1.f + __expf(-fabsf(x)));
}
// exp2 (v_exp_f32 directly; log2e pre-folded into the coefficient)
__device__ __forceinline__ float exp2_fast(float x) {
#if __has_builtin(__builtin_amdgcn_exp2f)
    return __builtin_amdgcn_exp2f(x);
#else
    return __expf(x * 0.69314718055994531f);
#endif
}
#define LOG2E 1.44269504088896341f

__device__ __forceinline__ unsigned short f2bf(float f) {
    union { float f; uint32_t u; } v; v.f = f;
    const uint32_t u = v.u;
    return (unsigned short)((u + 0x7fffu + ((u >> 16) & 1u)) >> 16);  // RNE
}
__device__ __forceinline__ float bf2f(unsigned short h) {
    union { uint32_t u; float f; } v; v.u = ((uint32_t)h) << 16;
    return v.f;
}
__device__ __forceinline__ float bf2f_s(short h) { return bf2f((unsigned short)h); }

// async global -> LDS, 16 bytes per lane
__device__ __forceinline__ void load_lds16(const void* g, void* l) {
    __builtin_amdgcn_global_load_lds(
        (const __attribute__((address_space(1))) unsigned int*)g,
        (__attribute__((address_space(3))) unsigned int*)l,
        16, 0, 0);
}

// ---------------------------------------------------------------------------
// bf16 MFMA GEMM: acc = A[M,K] @ Bt[N,K]^T, 128 x NT tile, BK=64, 256 thr.
// Single-buffered staging; XOR-swizzled LDS; LDS-bounced coalesced epilogue.
// XCD-aware bijective block swizzle for per-XCD L2 locality.
//   EPI = 0: Obf = bf16(acc)
//   EPI = 2: v = acc + bf2f(Obf) (bf16 residual, in-place)
//   EPI = 3: as 2, plus column sums atomicAdd'ed into pool[b][col]
// ---------------------------------------------------------------------------
template <int K, int NT, int EPI>
__global__ __launch_bounds__(256) void gemm_bf16(
    const unsigned short* __restrict__ A, int lda,
    const unsigned short* __restrict__ Bt, int ldb,
    int ldc,
    unsigned short* __restrict__ Obf,
    float* __restrict__ pool)
{
    constexpr int BCH   = NT / 8;
    constexpr int NTW   = NT / 32;
    constexpr int STAGE = 8192 + NT * 64;
    constexpr int EPIL  = 128 * (NT + 8);
    constexpr int SMEM  = (STAGE > EPIL) ? STAGE : EPIL;
    __shared__ unsigned short sMem[SMEM];
    unsigned short* sA = sMem;
    unsigned short* sB = sMem + 8192;

    const int tid  = threadIdx.x;
    const int lane = tid & 63;
    const int wave = tid >> 6;

    // bijective XCD swizzle (8 XCDs)
    const int nwgx = gridDim.x;
    const int nwg  = nwgx * gridDim.y;
    int flat = blockIdx.y * nwgx + blockIdx.x;
    {
        const int q = nwg >> 3, r = nwg & 7;
        const int xcd = flat & 7, lid = flat >> 3;
        flat = (xcd < r ? xcd * (q + 1) : r * (q + 1) + (xcd - r) * q) + lid;
    }
    const int m0 = (flat / nwgx) * 128;
    const int n0 = (flat % nwgx) * NT;

    const int wm = (wave >> 1) * 64;
    const int wn = (wave & 1) * (NT / 2);
    const int lm = lane & 15;
    const int lq = lane >> 4;

    const int srow = lane >> 3;
    const int scol = ((lane & 7) ^ srow) * 8;

    f32x4 acc[4][NTW];
    #pragma unroll
    for (int i = 0; i < 4; ++i)
        #pragma unroll
        for (int j = 0; j < NTW; ++j) acc[i][j] = (f32x4){0.f, 0.f, 0.f, 0.f};

    for (int k0 = 0; k0 < K; k0 += 64) {
        #pragma unroll
        for (int c = wave; c < 16; c += 4)
            load_lds16(A + (size_t)(m0 + c * 8 + srow) * lda + k0 + scol, &sA[c * 512]);
        #pragma unroll
        for (int c = wave; c < BCH; c += 4)
            load_lds16(Bt + (size_t)(n0 + c * 8 + srow) * ldb + k0 + scol, &sB[c * 512]);
        __syncthreads();
        #pragma unroll
        for (int ks = 0; ks < 2; ++ks) {
            bf16x8 aF[4], bF[NTW];
            #pragma unroll
            for (int mt = 0; mt < 4; ++mt) {
                const int row = wm + mt * 16 + lm;
                aF[mt] = *(const bf16x8*)&sA[row * 64 + (((ks * 4 + lq) ^ (lm & 7)) * 8)];
            }
            #pragma unroll
            for (int nt = 0; nt < NTW; ++nt) {
                const int row = wn + nt * 16 + lm;
                bF[nt] = *(const bf16x8*)&sB[row * 64 + (((ks * 4 + lq) ^ (lm & 7)) * 8)];
            }
            #pragma unroll
            for (int mt = 0; mt < 4; ++mt)
                #pragma unroll
                for (int nt = 0; nt < NTW; ++nt)
                    acc[mt][nt] = __builtin_amdgcn_mfma_f32_16x16x32_bf16(
                        aF[mt], bF[nt], acc[mt][nt], 0, 0, 0);
        }
        __syncthreads();
    }

    unsigned short* sOut = sMem;
    #pragma unroll
    for (int mt = 0; mt < 4; ++mt) {
        #pragma unroll
        for (int nt = 0; nt < NTW; ++nt) {
            #pragma unroll
            for (int r = 0; r < 4; ++r) {
                const int row = wm + mt * 16 + lq * 4 + r;
                const int col = wn + nt * 16 + lm;
                float v = acc[mt][nt][r];
                if (EPI >= 2) {
                    const size_t gi = (size_t)(m0 + row) * ldc + n0 + col;
                    v += bf2f(Obf[gi]);   // bf16 residual read (write comes after barrier)
                }
                sOut[row * (NT + 8) + col] = f2bf(v);
            }
        }
    }
    __syncthreads();
    #pragma unroll
    for (int j = 0; j < NT / 16; ++j) {
        const int idx = j * 256 + tid;
        const int row = idx / (NT / 8);
        const int cpos = (idx % (NT / 8)) * 8;
        *(bf16x8*)&Obf[(size_t)(m0 + row) * ldc + n0 + cpos] =
            *(const bf16x8*)&sOut[row * (NT + 8) + cpos];
    }
    if (EPI == 3) {
        const int b = m0 >> 11;
        const int col = tid & (NT - 1);
        const int q = tid / NT;
        constexpr int RPQ = 128 / (256 / NT);
        float s = 0.f;
        #pragma unroll
        for (int r = q * RPQ; r < (q + 1) * RPQ; ++r)
            s += bf2f(sOut[r * (NT + 8) + col]);
        atomicAdd(&pool[b * DMODEL + n0 + col], s);
    }
}

// ---------------------------------------------------------------------------
// Fused conv+SiLU+x_proj: each block owns a 64-row x 128-col (d) tile.
// Phase 1: conv(K=4)+bias+SiLU -> swizzled LDS tile + coalesced ub write.
// Phase 2: Xp[split][rows][48] = tile @ Wxt[48, k-slice]^T via MFMA from LDS.
// ---------------------------------------------------------------------------
__global__ __launch_bounds__(256) void conv_xproj_kernel(
    const unsigned short* __restrict__ xz,
    const float* __restrict__ cwt,   // (4, 1024)
    const float* __restrict__ cb,
    const unsigned short* __restrict__ Wxt,
    unsigned short* __restrict__ ub,
    float* __restrict__ Xp)
{
    __shared__ unsigned short sU[64 * 128];   // 16 KB, XOR-swizzled chunks
    const int tid = threadIdx.x, lane = tid & 63, wave = tid >> 6;
    const int lm = lane & 15, lq = lane >> 4;
    const int row0 = blockIdx.x * 64;
    const int split = blockIdx.y;
    const int k0 = split * (DINNER / NSPLIT);   // 128-col d-slice

    // ---- Phase 1: conv + SiLU
    const int cj  = tid & 15;          // col chunk (8 cols each)
    const int rr0 = tid >> 4;          // row 0..15, + p*16
    const int dcol = k0 + cj * 8;
    float4 cb0 = *(const float4*)&cb[dcol];
    float4 cb1 = *(const float4*)&cb[dcol + 4];
    float4 w0[KCONV], w1[KCONV];
    #pragma unroll
    for (int k = 0; k < KCONV; ++k) {
        w0[k] = *(const float4*)&cwt[k * DINNER + dcol];
        w1[k] = *(const float4*)&cwt[k * DINNER + dcol + 4];
    }
    #pragma unroll
    for (int p = 0; p < 4; ++p) {
        const int rl = p * 16 + rr0;
        const int m  = row0 + rl;
        const int t  = m & (L_SEQ - 1);
        float acc[8];
        acc[0] = cb0.x; acc[1] = cb0.y; acc[2] = cb0.z; acc[3] = cb0.w;
        acc[4] = cb1.x; acc[5] = cb1.y; acc[6] = cb1.z; acc[7] = cb1.w;
        #pragma unroll
        for (int k = 0; k < KCONV; ++k) {
            if (t + k - (KCONV - 1) >= 0) {
                bf16x8 xv = *(const bf16x8*)&xz[(size_t)(m + k - (KCONV - 1)) * (2 * DINNER) + dcol];
                acc[0] = fmaf(bf2f_s(xv[0]), w0[k].x, acc[0]);
                acc[1] = fmaf(bf2f_s(xv[1]), w0[k].y, acc[1]);
                acc[2] = fmaf(bf2f_s(xv[2]), w0[k].z, acc[2]);
                acc[3] = fmaf(bf2f_s(xv[3]), w0[k].w, acc[3]);
                acc[4] = fmaf(bf2f_s(xv[4]), w1[k].x, acc[4]);
                acc[5] = fmaf(bf2f_s(xv[5]), w1[k].y, acc[5]);
                acc[6] = fmaf(bf2f_s(xv[6]), w1[k].z, acc[6]);
                acc[7] = fmaf(bf2f_s(xv[7]), w1[k].w, acc[7]);
            }
        }
        bf16x8 o;
        #pragma unroll
        for (int j = 0; j < 8; ++j) o[j] = (short)f2bf(silu_fast(acc[j]));
        *(bf16x8*)&ub[(size_t)m * DINNER + dcol] = o;
        *(bf16x8*)&sU[rl * 128 + ((cj ^ (rl & 7)) * 8)] = o;
    }
    __syncthreads();

    // ---- Phase 2: MFMA x_proj from LDS tile
    const int rowA = row0 + wave * 16;
    f32x4 acc3[3];
    #pragma unroll
    for (int j = 0; j < 3; ++j) acc3[j] = (f32x4){0.f, 0.f, 0.f, 0.f};

    #pragma unroll
    for (int kk = 0; kk < DINNER / NSPLIT; kk += 32) {
        const int rl = wave * 16 + lm;
        bf16x8 aF = *(const bf16x8*)&sU[rl * 128 + ((((kk >> 3) + lq) ^ (lm & 7)) * 8)];
        bf16x8 bF[3];
        #pragma unroll
        for (int nt = 0; nt < 3; ++nt)
            bF[nt] = *(const bf16x8*)&Wxt[(size_t)(nt * 16 + lm) * DINNER + k0 + kk + lq * 8];
        #pragma unroll
        for (int nt = 0; nt < 3; ++nt)
            acc3[nt] = __builtin_amdgcn_mfma_f32_16x16x32_bf16(
                aF, bF[nt], acc3[nt], 0, 0, 0);
    }
    float* dst = Xp + (size_t)split * MROWS * DBLW;
    #pragma unroll
    for (int nt = 0; nt < 3; ++nt)
        #pragma unroll
        for (int r = 0; r < 4; ++r)
            dst[(size_t)(rowA + lq * 4 + r) * DBLW + nt * 16 + lm] = acc3[nt][r];
}

// ---------------------------------------------------------------------------
// Weight transpose + cast: out[n][k] bf16 = in[k][n] fp32
// ---------------------------------------------------------------------------
__global__ __launch_bounds__(256) void transpose_cast(
    const float* __restrict__ in, unsigned short* __restrict__ out,
    int Kdim, int Ndim, size_t in_stride, size_t out_stride)
{
    __shared__ float s[32][33];
    const float* ip = in + blockIdx.z * in_stride;
    unsigned short* op = out + blockIdx.z * out_stride;
    const int bx = blockIdx.x * 32;
    const int by = blockIdx.y * 32;
    const int t = threadIdx.x;
    const int r = t >> 3;
    const int c4 = (t & 7) * 4;

    const int row = by + r;
    if (bx + c4 + 3 < Ndim) {
        float4 v = *(const float4*)&ip[(size_t)row * Ndim + bx + c4];
        s[r][c4 + 0] = v.x; s[r][c4 + 1] = v.y; s[r][c4 + 2] = v.z; s[r][c4 + 3] = v.w;
    } else {
        for (int i = 0; i < 4; ++i) {
            const int col = bx + c4 + i;
            s[r][c4 + i] = (col < Ndim) ? ip[(size_t)row * Ndim + col] : 0.f;
        }
    }
    __syncthreads();
    if (bx + r < Ndim) {
        unsigned short w0 = f2bf(s[c4 + 0][r]), w1 = f2bf(s[c4 + 1][r]);
        unsigned short w2 = f2bf(s[c4 + 2][r]), w3 = f2bf(s[c4 + 3][r]);
        uint2 pk;
        pk.x = (uint32_t)w0 | ((uint32_t)w1 << 16);
        pk.y = (uint32_t)w2 | ((uint32_t)w3 << 16);
        *(uint2*)&op[(size_t)(bx + r) * Kdim + by + c4] = pk;
    }
}

// cast x -> xb (bf16); zero pooled_accum; negA prep; conv-w transpose.
__global__ void cast_init(const float* __restrict__ in, unsigned short* __restrict__ outb,
                          float* __restrict__ pooled_accum,
                          const float* __restrict__ A_log, float* __restrict__ negA,
                          const float* __restrict__ cw, float* __restrict__ cwt,
                          int n4) {
    const int i = blockIdx.x * 256 + threadIdx.x;
    if (i < BATCH_N * DMODEL / 4)
        ((f32x4*)pooled_accum)[i] = (f32x4){0.f, 0.f, 0.f, 0.f};
    if (i < NBLK * DINNER * DSTATE)
        negA[i] = -__expf(A_log[i]) * LOG2E;
    if (i < NBLK * DINNER * KCONV) {
        const int blk = i >> 12;
        const int rem = i & 4095;
        const int d = rem >> 2;
        const int k = rem & 3;
        cwt[blk * 4096 + k * DINNER + d] = cw[blk * 4096 + d * KCONV + k];
    }
    if (i >= n4) return;
    float4 v = ((const float4*)in)[i];
    uint2 pk;
    pk.x = (uint32_t)f2bf(v.x) | ((uint32_t)f2bf(v.y) << 16);
    pk.y = (uint32_t)f2bf(v.z) | ((uint32_t)f2bf(v.w) << 16);
    ((uint2*)outb)[i] = pk;
}

// ---------------------------------------------------------------------------
// dt-proj recompute into LDS for one d-half, reading the reduced x_proj rows
// from the block-local sDbl tile (row stride DBLP). 32 MFMAs/block (4/wave).
// ---------------------------------------------------------------------------
__device__ __forceinline__ void dt_recompute_lds(
    unsigned short* sDelta,                  // LC2 * DHALF bf16
    const float* sDbl,                       // LC2 x DBLP (LDS)
    const unsigned short* __restrict__ Wdtt, // (1024, 32) bf16
    const float* __restrict__ bdt,
    int lane, int wave, int dbase)
{
    const int lm = lane & 15, lq = lane >> 4;
    bf16x8 aF;
    {
        const float* p = &sDbl[lm * DBLP + lq * 8];
        float4 x0 = *(const float4*)p;
        float4 x1 = *(const float4*)(p + 4);
        aF[0] = (short)f2bf(x0.x); aF[1] = (short)f2bf(x0.y);
        aF[2] = (short)f2bf(x0.z); aF[3] = (short)f2bf(x0.w);
        aF[4] = (short)f2bf(x1.x); aF[5] = (short)f2bf(x1.y);
        aF[6] = (short)f2bf(x1.z); aF[7] = (short)f2bf(x1.w);
    }
    constexpr int NPW = DHALF / (16 * SCAN_WAVES);   // 4 col16-tiles per wave
    #pragma unroll
    for (int nt = 0; nt < NPW; ++nt) {
        const int cloc = wave * (DHALF / SCAN_WAVES) + nt * 16;   // local col
        const int col16 = dbase + cloc;
        bf16x8 bF = *(const bf16x8*)&Wdtt[(size_t)(col16 + lm) * DTRANK + lq * 8];
        f32x4 acc = (f32x4){0.f, 0.f, 0.f, 0.f};
        acc = __builtin_amdgcn_mfma_f32_16x16x32_bf16(aF, bF, acc, 0, 0, 0);
        const float bias = bdt[col16 + lm];
        #pragma unroll
        for (int r = 0; r < 4; ++r)
            sDelta[(lq * 4 + r) * DHALF + cloc + lm] =
                f2bf(softplus_fast(acc[r] + bias));
    }
}

// Stage the 8-way-reduced x_proj rows for this chunk into sDbl[16][DBLP].
// Same summation order (sp = 0..7) as before -> bit-identical.
__device__ __forceinline__ void stage_dbl_rows(
    float* sDbl, const float* __restrict__ Xp, size_t m0, int tid)
{
    for (int idx = tid; idx < LC2 * DBLW; idx += SCAN_THREADS) {
        const int mr = idx / DBLW, j = idx - mr * DBLW;
        float s = 0.f;
        #pragma unroll
        for (int sp = 0; sp < NSPLIT; ++sp)
            s += Xp[((size_t)sp * MROWS + m0 + mr) * DBLW + j];
        sDbl[mr * DBLP + j] = s;
    }
}

// Detect a[n] == (n+1)*a[0] (canonical Mamba A_log = log(arange(1..N)) init);
// falls back to the general 8-exp path when the structure doesn't hold.
__device__ __forceinline__ bool a_is_arange(const float* a) {
    bool pw = true;
    #pragma unroll
    for (int n = 1; n < DSTATE; ++n)
        pw = pw && (fabsf(a[n] - (float)(n + 1) * a[0]) <=
                    1e-5f * (float)(n + 1) * fabsf(a[0]));
    return pw;
}

// ---------------------------------------------------------------------------
// 3-phase chunked selective scan; 512 threads, 1 channel/thread, d split x2.
// Grid (NC2, 2, BATCH) = 1024 blocks -> 4 blocks/CU, 32 waves/CU.
// PSbuf stores S only; P is recomputed in the combine from dtsum + negA
// (P == exp2(a[n]*dtsum) by construction), halving scan-chain traffic.
// ---------------------------------------------------------------------------
__global__ __launch_bounds__(SCAN_THREADS) void scan_chunk_kernel(
    const unsigned short* __restrict__ ub,
    const float* __restrict__ Xp,
    const unsigned short* __restrict__ Wdtt,
    const float* __restrict__ bdt,
    const float* __restrict__ negA,          // (1024, 8) = -exp(A_log)*log2e
    float* __restrict__ Sbuf,                // (B*NC2*DSTATE, DINNER)
    float* __restrict__ Dtsum)               // (B*NC2, DINNER)
{
    const int c  = blockIdx.x;
    const int dh = blockIdx.y;
    const int b  = blockIdx.z;
    const int tid = threadIdx.x;
    const int lane = tid & 63;
    const int wave = tid >> 6;
    const int dbase = dh * DHALF;
    const int d = dbase + tid;

    __shared__ unsigned short sDelta[LC2 * DHALF];
    __shared__ float sDbl[LC2 * DBLP];

    const size_t m0 = (size_t)b * L_SEQ + c * LC2;

    stage_dbl_rows(sDbl, Xp, m0, tid);
    __syncthreads();
    dt_recompute_lds(sDelta, sDbl, Wdtt, bdt, lane, wave, dbase);
    __syncthreads();

    float a[DSTATE], S[DSTATE];
    {
        float4 a0 = *(const float4*)&negA[(size_t)d * DSTATE];
        float4 a1 = *(const float4*)&negA[(size_t)d * DSTATE + 4];
        a[0] = a0.x; a[1] = a0.y; a[2] = a0.z; a[3] = a0.w;
        a[4] = a1.x; a[5] = a1.y; a[6] = a1.z; a[7] = a1.w;
    }
    #pragma unroll
    for (int n = 0; n < DSTATE; ++n) S[n] = 0.f;
    float dtsum = 0.f;

    if (a_is_arange(a)) {
        for (int r = 0; r < LC2; ++r) {
            const size_t m = m0 + r;
            const float dt = bf2f(sDelta[r * DHALF + tid]);
            const float du = dt * bf2f(ub[m * DINNER + d]);
            dtsum += dt;
            const float e1 = exp2_fast(dt * a[0]);
            float e = e1;
            #pragma unroll
            for (int n = 0; n < DSTATE; ++n) {
                S[n] = fmaf(e, S[n], du * sDbl[r * DBLP + DTRANK + n]);
                e *= e1;
            }
        }
    } else {
        for (int r = 0; r < LC2; ++r) {
            const size_t m = m0 + r;
            const float dt = bf2f(sDelta[r * DHALF + tid]);
            const float du = dt * bf2f(ub[m * DINNER + d]);
            dtsum += dt;
            #pragma unroll
            for (int n = 0; n < DSTATE; ++n) {
                const float e = exp2_fast(dt * a[n]);
                S[n] = fmaf(e, S[n], du * sDbl[r * DBLP + DTRANK + n]);
            }
        }
    }
    const size_t rc = (size_t)(b * NC2 + c);
    #pragma unroll
    for (int n = 0; n < DSTATE; ++n)
        Sbuf[(rc * DSTATE + n) * DINNER + d] = S[n];
    Dtsum[rc * DINNER + d] = dtsum;
}

// Combine: h-recurrence over chunks, 2-level (8 waves x 16-chunk segments).
// P recomputed as exp2(negA[d,n] * dtsum); segment values register-cached.
__global__ __launch_bounds__(512) void scan_combine_kernel(
    const float* __restrict__ Sbuf,
    const float* __restrict__ Dtsum,
    const float* __restrict__ negA,
    float* __restrict__ Hbuf)
{
    const int dl = threadIdx.x & 63;
    const int g  = threadIdx.x >> 6;
    const int d  = blockIdx.x * 64 + dl;
    const int n  = blockIdx.y;
    const int b  = blockIdx.z;

    __shared__ float sP[CGRP][64];
    __shared__ float sS[CGRP][64];

    const float an = negA[(size_t)d * DSTATE + n];
    const int c0 = g * CPG;
    float pr[CPG], sr[CPG];
    float Pseg = 1.f, Sseg = 0.f;
    #pragma unroll
    for (int cc = 0; cc < CPG; ++cc) {
        const size_t rc = (size_t)(b * NC2 + c0 + cc);
        pr[cc] = exp2_fast(an * Dtsum[rc * DINNER + d]);
        sr[cc] = Sbuf[(rc * DSTATE + n) * DINNER + d];
        Pseg *= pr[cc];
        Sseg = fmaf(pr[cc], Sseg, sr[cc]);
    }
    sP[g][dl] = Pseg;
    sS[g][dl] = Sseg;
    __syncthreads();

    float h = 0.f;
    for (int gg = 0; gg < g; ++gg)            // wave-uniform trip count
        h = fmaf(sP[gg][dl], h, sS[gg][dl]);

    #pragma unroll
    for (int cc = 0; cc < CPG; ++cc) {
        const size_t row = ((size_t)(b * NC2 + c0 + cc) * DSTATE + n);
        Hbuf[row * DINNER + d] = h;
        h = fmaf(pr[cc], h, sr[cc]);
    }
}

__global__ __launch_bounds__(SCAN_THREADS) void scan_out_kernel(
    const unsigned short* __restrict__ ub,
    const float* __restrict__ Xp,
    const unsigned short* __restrict__ Wdtt,
    const float* __restrict__ bdt,
    const unsigned short* __restrict__ xz,   // z at [., 1024+d]
    const float* __restrict__ negA,
    const float* __restrict__ Dp,
    const float* __restrict__ Hin,
    unsigned short* __restrict__ ybuf)
{
    const int c  = blockIdx.x;
    const int dh = blockIdx.y;
    const int b  = blockIdx.z;
    const int tid = threadIdx.x;
    const int lane = tid & 63;
    const int wave = tid >> 6;
    const int dbase = dh * DHALF;
    const int d = dbase + tid;

    __shared__ unsigned short sDelta[LC2 * DHALF];
    __shared__ float sDbl[LC2 * DBLP];

    const size_t m0 = (size_t)b * L_SEQ + c * LC2;

    stage_dbl_rows(sDbl, Xp, m0, tid);
    __syncthreads();
    dt_recompute_lds(sDelta, sDbl, Wdtt, bdt, lane, wave, dbase);
    __syncthreads();

    float a[DSTATE], h[DSTATE];
    {
        float4 a0 = *(const float4*)&negA[(size_t)d * DSTATE];
        float4 a1 = *(const float4*)&negA[(size_t)d * DSTATE + 4];
        a[0] = a0.x; a[1] = a0.y; a[2] = a0.z; a[3] = a0.w;
        a[4] = a1.x; a[5] = a1.y; a[6] = a1.z; a[7] = a1.w;
    }
    const size_t base = ((size_t)(b * NC2 + c) * DSTATE) * DINNER + d;
    #pragma unroll
    for (int n = 0; n < DSTATE; ++n)
        h[n] = Hin[base + (size_t)n * DINNER];
    const float Dd = Dp[d];

    if (a_is_arange(a)) {
        for (int r = 0; r < LC2; ++r) {
            const size_t m = m0 + r;
            const float dt = bf2f(sDelta[r * DHALF + tid]);
            const float ut = bf2f(ub[m * DINNER + d]);
            const float zt = bf2f(xz[m * (2 * DINNER) + DINNER + d]);
            const float du = dt * ut;
            const float e1 = exp2_fast(dt * a[0]);
            float e = e1;
            float acc = 0.f;
            #pragma unroll
            for (int n = 0; n < DSTATE; ++n) {
                h[n] = fmaf(e, h[n], du * sDbl[r * DBLP + DTRANK + n]);
                acc = fmaf(h[n], sDbl[r * DBLP + DTRANK + DSTATE + n], acc);
                e *= e1;
            }
            ybuf[m * DINNER + d] = f2bf(fmaf(ut, Dd, acc) * silu_fast(zt));
        }
    } else {
        for (int r = 0; r < LC2; ++r) {
            const size_t m = m0 + r;
            const float dt = bf2f(sDelta[r * DHALF + tid]);
            const float ut = bf2f(ub[m * DINNER + d]);
            const float zt = bf2f(xz[m * (2 * DINNER) + DINNER + d]);
            const float du = dt * ut;
            float acc = 0.f;
            #pragma unroll
            for (int n = 0; n < DSTATE; ++n) {
                const float e = exp2_fast(dt * a[n]);
                h[n] = fmaf(e, h[n], du * sDbl[r * DBLP + DTRANK + n]);
                acc = fmaf(h[n], sDbl[r * DBLP + DTRANK + DSTATE + n], acc);
            }
            ybuf[m * DINNER + d] = f2bf(fmaf(ut, Dd, acc) * silu_fast(zt));
        }
    }
}

// ---------------------------------------------------------------------------
// pooled-sum (from fused out_proj accumulation) + classifier
// ---------------------------------------------------------------------------
__global__ __launch_bounds__(512) void pool_cls_kernel(
    const float* __restrict__ pooled_accum,   // (B, 512) sums over t
    const float* __restrict__ w,              // (512, 10)
    const float* __restrict__ bias,           // (10,)
    float* __restrict__ out)
{
    __shared__ float sp[DMODEL];
    const int b = blockIdx.x;
    const int dm = threadIdx.x;
    sp[dm] = pooled_accum[b * DMODEL + dm] * (1.f / (float)L_SEQ);
    __syncthreads();
    if (dm < NCLS_N) {
        float acc = bias[dm];
        for (int k = 0; k < DMODEL; ++k)
            acc = fmaf(sp[k], w[k * NCLS_N + dm], acc);
        out[b * NCLS_N + dm] = acc;
    }
}

// ---------------------------------------------------------------------------
extern "C" void kernel_launch(void* const* d_in, const int* in_sizes, int n_in,
                              void* d_out, int out_size, void* d_ws, size_t ws_size,
                              hipStream_t stream) {
    const float* x_in      = (const float*)d_in[0];
    const float* in_proj_w = (const float*)d_in[1];
    const float* conv_w    = (const float*)d_in[2];
    const float* conv_b    = (const float*)d_in[3];
    const float* x_proj_w  = (const float*)d_in[4];
    const float* dt_proj_w = (const float*)d_in[5];
    const float* dt_proj_b = (const float*)d_in[6];
    const float* A_log     = (const float*)d_in[7];
    const float* Dp        = (const float*)d_in[8];
    const float* out_proj_w= (const float*)d_in[9];
    const float* cls_w     = (const float*)d_in[10];
    const float* cls_b     = (const float*)d_in[11];
    float* out = (float*)d_out;

    // Workspace layout (bytes, 256-aligned)
    char* w = (char*)d_ws;
    auto alloc = [&](size_t bytes) { char* p = w; w += (bytes + 255) & ~(size_t)255; return p; };
    unsigned short* xz_bf  = (unsigned short*)alloc((size_t)MROWS * 2 * DINNER * 2);
    unsigned short* ub     = (unsigned short*)alloc((size_t)MROWS * DINNER * 2);
    float*          Xp     = (float*)         alloc((size_t)NSPLIT * MROWS * DBLW * 4);
    float*          Sbuf   = (float*)         alloc((size_t)BATCH_N * NC2 * DSTATE * DINNER * 4);
    float*          Dtsum  = (float*)         alloc((size_t)BATCH_N * NC2 * DINNER * 4);
    float*          Hbuf   = (float*)         alloc((size_t)BATCH_N * NC2 * DSTATE * DINNER * 4);
    unsigned short* xb     = (unsigned short*)alloc((size_t)MROWS * DMODEL * 2);
    unsigned short* ybuf   = (unsigned short*)alloc((size_t)MROWS * DINNER * 2);
    unsigned short* Wit    = (unsigned short*)alloc((size_t)NBLK * 2048 * 512 * 2);
    unsigned short* Wot    = (unsigned short*)alloc((size_t)NBLK * 512 * 1024 * 2);
    unsigned short* Wxt    = (unsigned short*)alloc((size_t)NBLK * DBLW * 1024 * 2);
    unsigned short* Wdtt   = (unsigned short*)alloc((size_t)NBLK * 1024 * DTRANK * 2);
    float*          cwt    = (float*)         alloc((size_t)NBLK * KCONV * DINNER * 4);
    float*          negA   = (float*)         alloc((size_t)NBLK * DINNER * DSTATE * 4);
    float*          pooled = (float*)         alloc((size_t)BATCH_N * DMODEL * 4);

    // Prep (cast_init also zeroes pooled, builds negA and cwt)
    cast_init<<<(MROWS * DMODEL / 4) / 256, 256, 0, stream>>>(
        x_in, xb, pooled, A_log, negA, conv_w, cwt, MROWS * DMODEL / 4);
    transpose_cast<<<dim3(2048 / 32, 512 / 32, NBLK), 256, 0, stream>>>(
        in_proj_w, Wit, 512, 2048, (size_t)512 * 2048, (size_t)2048 * 512);
    transpose_cast<<<dim3(512 / 32, 1024 / 32, NBLK), 256, 0, stream>>>(
        out_proj_w, Wot, 1024, 512, (size_t)1024 * 512, (size_t)512 * 1024);
    transpose_cast<<<dim3(2, 1024 / 32, NBLK), 256, 0, stream>>>(
        x_proj_w, Wxt, 1024, DBLW, (size_t)1024 * DBLW, (size_t)DBLW * 1024);
    transpose_cast<<<dim3(1024 / 32, 1, NBLK), 256, 0, stream>>>(
        dt_proj_w, Wdtt, DTRANK, 1024, (size_t)DTRANK * 1024, (size_t)1024 * DTRANK);

    for (int blk = 0; blk < NBLK; ++blk) {
        const unsigned short* Wit_b  = Wit  + (size_t)blk * 2048 * 512;
        const unsigned short* Wot_b  = Wot  + (size_t)blk * 512 * 1024;
        const unsigned short* Wxt_b  = Wxt  + (size_t)blk * DBLW * 1024;
        const unsigned short* Wdtt_b = Wdtt + (size_t)blk * 1024 * DTRANK;
        const float* cwt_b = cwt + (size_t)blk * KCONV * DINNER;
        const float* cb  = conv_b    + (size_t)blk * DINNER;
        const float* bdt = dt_proj_b + (size_t)blk * DINNER;
        const float* nA  = negA      + (size_t)blk * DINNER * DSTATE;
        const float* Dv  = Dp        + (size_t)blk * DINNER;

        // 1) xz_bf = bf16(xb @ Wit^T)   K=512, 128x128 tiles
        gemm_bf16<512, 128, 0><<<dim3(2048 / 128, MROWS / 128), 256, 0, stream>>>(
            xb, DMODEL, Wit_b, DMODEL, 2 * DINNER, xz_bf, nullptr);
        // 2+3) fused conv+SiLU -> ub, then Xp[s] partials from LDS tile
        conv_xproj_kernel<<<dim3(MROWS / 64, NSPLIT), 256, 0, stream>>>(
            xz_bf, cwt_b, cb, Wxt_b, ub, Xp);
        // 4) chunked scan; LC2=16, d split x2; S+dtsum (P derived in combine)
        {
            dim3 gridA(NC2, 2, BATCH_N);
            scan_chunk_kernel<<<gridA, SCAN_THREADS, 0, stream>>>(
                ub, Xp, Wdtt_b, bdt, nA, Sbuf, Dtsum);
            scan_combine_kernel<<<dim3(DINNER / 64, DSTATE, BATCH_N), 512, 0, stream>>>(
                Sbuf, Dtsum, nA, Hbuf);
            scan_out_kernel<<<gridA, SCAN_THREADS, 0, stream>>>(
                ub, Xp, Wdtt_b, bdt, xz_bf, nA, Dv, Hbuf, ybuf);
        }
        // 5) xb += ybuf @ Wot^T (bf16 residual in-place); last block also
        //    accumulates the mean-pool column sums into pooled[]
        if (blk < NBLK - 1)
            gemm_bf16<1024, 64, 2><<<dim3(DMODEL / 64, MROWS / 128), 256, 0, stream>>>(
                ybuf, DINNER, Wot_b, DINNER, DMODEL, xb, nullptr);
        else
            gemm_bf16<1024, 64, 3><<<dim3(DMODEL / 64, MROWS / 128), 256, 0, stream>>>(
                ybuf, DINNER, Wot_b, DINNER, DMODEL, xb, pooled);
    }

    // classifier on pooled sums
    pool_cls_kernel<<<BATCH_N, DMODEL, 0, stream>>>(pooled, cls_w, cls_b, out);
}